// Round 1
// baseline (1046.978 us; speedup 1.0000x reference)
//
#include <hip/hip_runtime.h>
#include <hip/hip_bf16.h>

// Problem constants (from reference setup_inputs)
#define BATCH 4
#define NQ 512
#define NK 4096
#define DIM 512
#define NH 8
#define HDIM 64

// ---------------------------------------------------------------------------
// Generic fp32 GEMM: Y[M,N] = X[M,K] @ W[N,K]^T + bias[N]
// BM=BN=64, BK=32, 256 threads, 4x4 outputs/thread.
// ---------------------------------------------------------------------------
__global__ __launch_bounds__(256)
void gemm_xwt(const float* __restrict__ X, const float* __restrict__ W,
              const float* __restrict__ bias, float* __restrict__ Y,
              int M, int K, int N) {
    __shared__ float Xs[32][64 + 4];   // [k][m], +4 pad keeps float4 alignment
    __shared__ float Ws[32][64 + 4];   // [k][n]
    const int t  = threadIdx.x;
    const int tm = t >> 4;             // 0..15
    const int tn = t & 15;             // 0..15
    const int m0 = blockIdx.y * 64;
    const int n0 = blockIdx.x * 64;
    const int r  = t >> 3;             // 0..31 (load row within half-tile)
    const int c4 = t & 7;              // 0..7  (float4 col)

    float acc[4][4] = {};

    for (int k0 = 0; k0 < K; k0 += 32) {
#pragma unroll
        for (int p = 0; p < 2; ++p) {
            const int row = p * 32 + r;
            float4 xv = *reinterpret_cast<const float4*>(X + (size_t)(m0 + row) * K + k0 + c4 * 4);
            Xs[c4 * 4 + 0][row] = xv.x; Xs[c4 * 4 + 1][row] = xv.y;
            Xs[c4 * 4 + 2][row] = xv.z; Xs[c4 * 4 + 3][row] = xv.w;
            float4 wv = *reinterpret_cast<const float4*>(W + (size_t)(n0 + row) * K + k0 + c4 * 4);
            Ws[c4 * 4 + 0][row] = wv.x; Ws[c4 * 4 + 1][row] = wv.y;
            Ws[c4 * 4 + 2][row] = wv.z; Ws[c4 * 4 + 3][row] = wv.w;
        }
        __syncthreads();
#pragma unroll
        for (int k = 0; k < 32; ++k) {
            float4 av = *reinterpret_cast<const float4*>(&Xs[k][tm * 4]);
            float4 bv = *reinterpret_cast<const float4*>(&Ws[k][tn * 4]);
            const float a[4] = {av.x, av.y, av.z, av.w};
            const float b[4] = {bv.x, bv.y, bv.z, bv.w};
#pragma unroll
            for (int i = 0; i < 4; ++i)
#pragma unroll
                for (int j = 0; j < 4; ++j)
                    acc[i][j] = fmaf(a[i], b[j], acc[i][j]);
        }
        __syncthreads();
    }

#pragma unroll
    for (int i = 0; i < 4; ++i) {
        const int row = m0 + tm * 4 + i;
        float4 o;
        o.x = acc[i][0] + bias[n0 + tn * 4 + 0];
        o.y = acc[i][1] + bias[n0 + tn * 4 + 1];
        o.z = acc[i][2] + bias[n0 + tn * 4 + 2];
        o.w = acc[i][3] + bias[n0 + tn * 4 + 3];
        *reinterpret_cast<float4*>(Y + (size_t)row * N + n0 + tn * 4) = o;
    }
}

// ---------------------------------------------------------------------------
// Scores: S[b,h,q,k] = 0.125 * sum_d Q[b,q,h*64+d] * K[b,k,h*64+d]
// Per block: one (b,h), 64 q-rows x 64 k-cols, K-dim = 64 staged fully.
// ---------------------------------------------------------------------------
__global__ __launch_bounds__(256)
void score_kernel(const float* __restrict__ Qp, const float* __restrict__ Kp,
                  float* __restrict__ S) {
    __shared__ float Qs[HDIM][64 + 4];  // [d][q]
    __shared__ float Ks[HDIM][64 + 4];  // [d][k]
    const int t  = threadIdx.x;
    const int tm = t >> 4;
    const int tn = t & 15;
    const int kt = blockIdx.x;          // 0..63
    const int qt = blockIdx.y;          // 0..7
    const int bh = blockIdx.z;          // 0..31
    const int b  = bh >> 3;
    const int h  = bh & 7;

    // load 64x64 tiles (4096 floats each) = 4 float4 per thread
#pragma unroll
    for (int p = 0; p < 4; ++p) {
        const int idx = p * 256 + t;
        const int row = idx >> 4;        // 0..63
        const int c4  = idx & 15;        // 0..15
        float4 qv = *reinterpret_cast<const float4*>(
            Qp + (size_t)(b * NQ + qt * 64 + row) * DIM + h * HDIM + c4 * 4);
        Qs[c4 * 4 + 0][row] = qv.x; Qs[c4 * 4 + 1][row] = qv.y;
        Qs[c4 * 4 + 2][row] = qv.z; Qs[c4 * 4 + 3][row] = qv.w;
        float4 kv = *reinterpret_cast<const float4*>(
            Kp + (size_t)(b * NK + kt * 64 + row) * DIM + h * HDIM + c4 * 4);
        Ks[c4 * 4 + 0][row] = kv.x; Ks[c4 * 4 + 1][row] = kv.y;
        Ks[c4 * 4 + 2][row] = kv.z; Ks[c4 * 4 + 3][row] = kv.w;
    }
    __syncthreads();

    float acc[4][4] = {};
#pragma unroll
    for (int d = 0; d < HDIM; ++d) {
        float4 av = *reinterpret_cast<const float4*>(&Qs[d][tm * 4]);
        float4 bv = *reinterpret_cast<const float4*>(&Ks[d][tn * 4]);
        const float a[4] = {av.x, av.y, av.z, av.w};
        const float b2[4] = {bv.x, bv.y, bv.z, bv.w};
#pragma unroll
        for (int i = 0; i < 4; ++i)
#pragma unroll
            for (int j = 0; j < 4; ++j)
                acc[i][j] = fmaf(a[i], b2[j], acc[i][j]);
    }

#pragma unroll
    for (int i = 0; i < 4; ++i) {
        const size_t row = (size_t)(bh * NQ + qt * 64 + tm * 4 + i);
        float4 o;
        o.x = acc[i][0] * 0.125f; o.y = acc[i][1] * 0.125f;
        o.z = acc[i][2] * 0.125f; o.w = acc[i][3] * 0.125f;
        *reinterpret_cast<float4*>(S + row * NK + kt * 64 + tn * 4) = o;
    }
}

// ---------------------------------------------------------------------------
// Row softmax in place over last dim (NK=4096). One block (256 thr) per row.
// Row held in registers (16 floats/thread) -> single read + single write.
// ---------------------------------------------------------------------------
__global__ __launch_bounds__(256)
void softmax_kernel(float* __restrict__ S) {
    float* p = S + (size_t)blockIdx.x * NK;
    const int t = threadIdx.x;
    __shared__ float redm[4];
    __shared__ float reds[4];

    float4 v[4];
    float mx = -INFINITY;
#pragma unroll
    for (int i = 0; i < 4; ++i) {
        v[i] = *reinterpret_cast<const float4*>(p + (i * 256 + t) * 4);
        mx = fmaxf(mx, fmaxf(fmaxf(v[i].x, v[i].y), fmaxf(v[i].z, v[i].w)));
    }
#pragma unroll
    for (int o = 1; o < 64; o <<= 1) mx = fmaxf(mx, __shfl_xor(mx, o, 64));
    const int wave = t >> 6, lane = t & 63;
    if (lane == 0) redm[wave] = mx;
    __syncthreads();
    mx = fmaxf(fmaxf(redm[0], redm[1]), fmaxf(redm[2], redm[3]));

    float s = 0.f;
#pragma unroll
    for (int i = 0; i < 4; ++i) {
        v[i].x = __expf(v[i].x - mx); v[i].y = __expf(v[i].y - mx);
        v[i].z = __expf(v[i].z - mx); v[i].w = __expf(v[i].w - mx);
        s += (v[i].x + v[i].y) + (v[i].z + v[i].w);
    }
#pragma unroll
    for (int o = 1; o < 64; o <<= 1) s += __shfl_xor(s, o, 64);
    if (lane == 0) reds[wave] = s;
    __syncthreads();
    const float inv = 1.f / (((reds[0] + reds[1]) + (reds[2] + reds[3])));
#pragma unroll
    for (int i = 0; i < 4; ++i) {
        v[i].x *= inv; v[i].y *= inv; v[i].z *= inv; v[i].w *= inv;
        *reinterpret_cast<float4*>(p + (i * 256 + t) * 4) = v[i];
    }
}

// ---------------------------------------------------------------------------
// ctx2[b,q,h*64+d] = sum_k A[b,h,q,k] * V[b,k,h*64+d]
// Per block: one (b,h), 64 q-rows x 64 d-cols, loop K=4096 in BK=32 chunks.
// ---------------------------------------------------------------------------
__global__ __launch_bounds__(256)
void ctx_kernel(const float* __restrict__ A, const float* __restrict__ Vp,
                float* __restrict__ ctx2) {
    __shared__ float As[32][64 + 4];   // [kk][q]
    __shared__ float Vs[32][64 + 4];   // [kk][d]
    const int t  = threadIdx.x;
    const int tm = t >> 4;
    const int tn = t & 15;
    const int qt = blockIdx.x;          // 0..7
    const int bh = blockIdx.y;          // 0..31
    const int b  = bh >> 3;
    const int h  = bh & 7;

    float acc[4][4] = {};
    const int r  = t >> 3;              // 0..31
    const int c4 = t & 7;               // 0..7

    for (int k0 = 0; k0 < NK; k0 += 32) {
        // A tile: 64 q x 32 k -> As[kk][q] (transposed stage)
#pragma unroll
        for (int p = 0; p < 2; ++p) {
            const int row = p * 32 + r;  // q within tile
            float4 av = *reinterpret_cast<const float4*>(
                A + (size_t)(bh * NQ + qt * 64 + row) * NK + k0 + c4 * 4);
            As[c4 * 4 + 0][row] = av.x; As[c4 * 4 + 1][row] = av.y;
            As[c4 * 4 + 2][row] = av.z; As[c4 * 4 + 3][row] = av.w;
        }
        // V tile: 32 k x 64 d -> Vs[kk][d] (direct stage)
#pragma unroll
        for (int p = 0; p < 2; ++p) {
            const int vrow = p * 16 + (t >> 4);  // 0..31
            const int vc4  = t & 15;
            float4 vv = *reinterpret_cast<const float4*>(
                Vp + (size_t)(b * NK + k0 + vrow) * DIM + h * HDIM + vc4 * 4);
            Vs[vrow][vc4 * 4 + 0] = vv.x; Vs[vrow][vc4 * 4 + 1] = vv.y;
            Vs[vrow][vc4 * 4 + 2] = vv.z; Vs[vrow][vc4 * 4 + 3] = vv.w;
        }
        __syncthreads();
#pragma unroll
        for (int kk = 0; kk < 32; ++kk) {
            float4 av = *reinterpret_cast<const float4*>(&As[kk][tm * 4]);
            float4 bv = *reinterpret_cast<const float4*>(&Vs[kk][tn * 4]);
            const float a[4] = {av.x, av.y, av.z, av.w};
            const float b2[4] = {bv.x, bv.y, bv.z, bv.w};
#pragma unroll
            for (int i = 0; i < 4; ++i)
#pragma unroll
                for (int j = 0; j < 4; ++j)
                    acc[i][j] = fmaf(a[i], b2[j], acc[i][j]);
        }
        __syncthreads();
    }

#pragma unroll
    for (int i = 0; i < 4; ++i) {
        const int q = qt * 64 + tm * 4 + i;
        *reinterpret_cast<float4*>(ctx2 + (size_t)(b * NQ + q) * DIM + h * HDIM + tn * 4) =
            make_float4(acc[i][0], acc[i][1], acc[i][2], acc[i][3]);
    }
}

// ---------------------------------------------------------------------------
extern "C" void kernel_launch(void* const* d_in, const int* in_sizes, int n_in,
                              void* d_out, int out_size, void* d_ws, size_t ws_size,
                              hipStream_t stream) {
    const float* query = (const float*)d_in[0];
    const float* key   = (const float*)d_in[1];
    const float* value = (const float*)d_in[2];
    const float* Wq    = (const float*)d_in[3];
    const float* bq    = (const float*)d_in[4];
    const float* Wk    = (const float*)d_in[5];
    const float* bk    = (const float*)d_in[6];
    const float* Wv    = (const float*)d_in[7];
    const float* bv    = (const float*)d_in[8];
    const float* Wo    = (const float*)d_in[9];
    const float* bo    = (const float*)d_in[10];

    float* out = (float*)d_out;                          // [4,512,512]
    float* A   = out + (size_t)BATCH * NQ * DIM;         // [4,8,512,4096]

    // workspace carve: Q(4MB) + K(32MB) + V(32MB) + ctx2(4MB) = 72MB
    float* Qp   = (float*)d_ws;
    float* Kp   = Qp + (size_t)BATCH * NQ * DIM;
    float* Vp   = Kp + (size_t)BATCH * NK * DIM;
    float* ctx2 = Vp + (size_t)BATCH * NK * DIM;
    (void)in_sizes; (void)n_in; (void)out_size; (void)ws_size;

    const int MQ = BATCH * NQ;   // 2048
    const int MK = BATCH * NK;   // 16384

    gemm_xwt<<<dim3(DIM / 64, MQ / 64), 256, 0, stream>>>(query, Wq, bq, Qp, MQ, DIM, DIM);
    gemm_xwt<<<dim3(DIM / 64, MK / 64), 256, 0, stream>>>(key,   Wk, bk, Kp, MK, DIM, DIM);
    gemm_xwt<<<dim3(DIM / 64, MK / 64), 256, 0, stream>>>(value, Wv, bv, Vp, MK, DIM, DIM);

    score_kernel<<<dim3(NK / 64, NQ / 64, BATCH * NH), 256, 0, stream>>>(Qp, Kp, A);
    softmax_kernel<<<BATCH * NH * NQ, 256, 0, stream>>>(A);
    ctx_kernel<<<dim3(NQ / 64, BATCH * NH), 256, 0, stream>>>(A, Vp, ctx2);

    gemm_xwt<<<dim3(DIM / 64, MQ / 64), 256, 0, stream>>>(ctx2, Wo, bo, out, MQ, DIM, DIM);
}